// Round 9
// baseline (5594.822 us; speedup 1.0000x reference)
//
#include <hip/hip_runtime.h>

typedef __bf16 bf16x8 __attribute__((ext_vector_type(8)));
typedef float f32x4 __attribute__((ext_vector_type(4)));
typedef unsigned short u16;
typedef u16 ushort8 __attribute__((ext_vector_type(8)));

#define BB 256
#define TT 512
#define II 64
#define HH 512
#define SLOT 131072   // u16 per h ring slot (256 KB)

// ws layout:
// [0x000000) h0ring : 4 * 256KB (fragment-order bf16)
// [0x100000) h1ring : 4 * 256KB
// [0x200000) h1fin  : 256*512 f32 (512KB)
// [0x280000) slotsA : 1024 u32 ; slotsB directly after (8KB total)
// [0x290000) xfrag  : 16 MB (optional)
#define OFF_H1RING 0x100000
#define OFF_H1FIN  0x200000
#define OFF_BAR    0x280000
#define OFF_XFRAG  0x290000
#define WS_NEED    (0x290000 + (size_t)(1 << 24))

__device__ __forceinline__ u16 f2bf(float f) {
  unsigned u = __builtin_bit_cast(unsigned, f);
  u = (u + 0x7FFFu + ((u >> 16) & 1u)) >> 16;   // RNE truncate to bf16
  return (u16)u;
}
__device__ __forceinline__ float sigmf(float v) {
  return 1.0f / (1.0f + __expf(-v));
}
__device__ __forceinline__ float tanh_s(float v) {
  float a = __builtin_fabsf(v);
  float e = __expf(-2.0f * a);
  float t = (1.0f - e) / (1.0f + e);
  return __builtin_copysignf(t, v);
}
__device__ __forceinline__ f32x4 mfma16(bf16x8 a, bf16x8 b, f32x4 c) {
  return __builtin_amdgcn_mfma_f32_16x16x32_bf16(a, b, c, 0, 0, 0);
}
// fragment-order offset (u16 units): chunk (R, kk, lane) of 8 bf16
__device__ __forceinline__ size_t fragoff(int R, int kk, int lane) {
  return ((size_t)(R * 16 + kk) * 64 + lane) * 8;
}
// agent-scope (cross-XCD coherent) 16B chunk load as 2x8B relaxed atomics
__device__ __forceinline__ bf16x8 ld_h8(const u16* p) {
  union { unsigned long long q[2]; ushort8 v; } u;
  u.q[0] = __hip_atomic_load((unsigned long long*)p, __ATOMIC_RELAXED,
                             __HIP_MEMORY_SCOPE_AGENT);
  u.q[1] = __hip_atomic_load((unsigned long long*)(p + 4), __ATOMIC_RELAXED,
                             __HIP_MEMORY_SCOPE_AGENT);
  return __builtin_bit_cast(bf16x8, u.v);
}
__device__ __forceinline__ bf16x8 ld_lds8(const u16* p) {
  return __builtin_bit_cast(bf16x8, *(const ushort8*)p);
}
// wave0 poll: lane l checks slots[4l..4l+3] (layout [ut][wid]) >= tgt
__device__ __forceinline__ void poll16(const unsigned* slots, unsigned tgt,
                                       int lane) {
  const unsigned long long* sl =
      (const unsigned long long*)slots + (size_t)lane * 2;
  for (;;) {
    unsigned long long q0 = __hip_atomic_load(sl, __ATOMIC_RELAXED,
                                              __HIP_MEMORY_SCOPE_AGENT);
    unsigned long long q1 = __hip_atomic_load(sl + 1, __ATOMIC_RELAXED,
                                              __HIP_MEMORY_SCOPE_AGENT);
    bool ok = ((unsigned)q0 >= tgt) && ((unsigned)(q0 >> 32) >= tgt) &&
              ((unsigned)q1 >= tgt) && ((unsigned)(q1 >> 32) >= tgt);
    if (__all(ok)) break;
    __builtin_amdgcn_s_sleep(2);
  }
}

__global__ void init_bar_k(unsigned* bar) {
  for (int i = threadIdx.x; i < 2048; i += blockDim.x) bar[i] = 0u;
}

// x -> fragment-order bf16: xfrag[t][R][kk][lane][8], one thread per chunk.
__global__ void xpose_k(const float* __restrict__ x, u16* __restrict__ xfrag) {
  const size_t idx = (size_t)blockIdx.x * 256 + threadIdx.x;  // 2^20 chunks
  const int lane = idx & 63;
  const int kk = (idx >> 6) & 1;
  const int R = (idx >> 7) & 15;
  const int t = (int)(idx >> 11);
  const int row = R * 16 + (lane & 15);
  const int col = kk * 32 + (lane >> 4) * 8;
  const float* src = x + ((size_t)row * TT + t) * II + col;
  ushort8 v;
#pragma unroll
  for (int j = 0; j < 8; ++j) v[j] = f2bf(src[j]);
  *(ushort8*)(xfrag + idx * 8) = v;
}

// Pipelined 2-layer LSTM: 512 WGs (2/CU). WGs 0-255 run layer0 only; WGs
// 256-511 run layer1 only, lagging 1 step. Rate = max(L0 step, L1 step).
// WG(bid&255): bt=bid>>6 (64 rows), ut=bid&63 (8 units); wave wid owns rows
// Rw=bt*4+wid (16 rows). Weights LDS-resident per role (W0 38KB / W1 66KB,
// one shared buffer). Flow control: monotonic slots A (h0) / B (h1), layout
// [bt][ut][wid]; per-wave arrive after vmcnt drain; wave0-only poll (16B/lane)
// relayed by __syncthreads. h0 ring 4-deep with L0 back-pressure B>=s-3
// (deadlock-free: L0_s <- L1_{s-4} <- L0_{s-4} <- ... terminates).
__global__ __launch_bounds__(256, 2) void lstm_split(
    const float* __restrict__ x, const u16* __restrict__ xfrag,
    const float* __restrict__ Wih0, const float* __restrict__ Whh0,
    const float* __restrict__ bih0, const float* __restrict__ bhh0,
    const float* __restrict__ Wih1, const float* __restrict__ Whh1,
    const float* __restrict__ bih1, const float* __restrict__ bhh1,
    u16* __restrict__ h0ring, u16* __restrict__ h1ring,
    float* __restrict__ h1fin, unsigned* __restrict__ slotsA,
    unsigned* __restrict__ slotsB) {
  __shared__ u16 wsm[32 * 1048];   // L0: stride 600; L1: stride 1048

  const int tid = threadIdx.x;
  const int lane = tid & 63;
  const int wid = tid >> 6;
  const bool isL1 = blockIdx.x >= 256;
  const int bid = blockIdx.x & 255;
  const int ut = bid & 63, bt = bid >> 6;
  const int u0 = ut * 8;
  const int cc = lane & 15, grp = lane >> 4;
  const int row0 = bt * 64 + wid * 16;
  const int Rw = bt * 4 + wid;
  const int kkw = ut >> 2, lpb = (ut & 3) * 16;   // writer chunk params
  const int lb = grp * 8;

  unsigned* myA = slotsA + (size_t)bt * 256;
  unsigned* myB = slotsB + (size_t)bt * 256;

  // ---- stage this role's weight slice into LDS as bf16 ----
  if (!isL1) {
    const int srow = tid >> 3, sub = tid & 7;
    const int g = (srow >> 3) * 512 + u0 + (srow & 7);
    const float* wih = Wih0 + (size_t)g * 64;
    const float* whh = Whh0 + (size_t)g * 512;
    const int e0 = sub * 72;
    for (int e = e0; e < e0 + 72; ++e) {
      float v = (e < 64) ? wih[e] : whh[e - 64];
      wsm[srow * 600 + e] = f2bf(v);
    }
  } else {
    const int srow = tid >> 3, sub = tid & 7;
    const int g = (srow >> 3) * 512 + u0 + (srow & 7);
    const float* wih = Wih1 + (size_t)g * 512;
    const float* whh = Whh1 + (size_t)g * 512;
    const int e0 = sub * 128;
    for (int e = e0; e < e0 + 128; ++e) {
      float v = (e < 512) ? wih[e] : whh[e - 512];
      wsm[srow * 1048 + e] = f2bf(v);
    }
  }
  __syncthreads();

  float bias[2];
#pragma unroll
  for (int nf = 0; nf < 2; ++nf) {
    const int srow = nf * 16 + cc;
    const int g = (srow >> 3) * 512 + u0 + (srow & 7);
    bias[nf] = isL1 ? (bih1[g] + bhh1[g]) : (bih0[g] + bhh0[g]);
  }

  float c[4] = {0.f, 0.f, 0.f, 0.f};
  bf16x8 hf[16];

  if (!isL1) {
    // ================= LAYER-0 WGs =================
    const int arow = row0 + cc;
    const float* xbase = x + (size_t)arow * (TT * II) + grp * 8;
    const bool usexf = (xfrag != nullptr);
    ushort8 xpre[2];
    float xr[16];
    if (usexf) {
#pragma unroll
      for (int kk = 0; kk < 2; ++kk)
        xpre[kk] = *(const ushort8*)(xfrag + (size_t)Rw * 1024 +
                                     (size_t)kk * 512 + lane * 8);
    } else {
#pragma unroll
      for (int j = 0; j < 16; ++j) xr[j] = xbase[(j >> 3) * 32 + (j & 7)];
    }

#pragma unroll 1
    for (int s = 0; s < 512; ++s) {
      if (wid == 0) {
        if (s >= 1) poll16(myA, (unsigned)s, lane);        // h0[s-1] visible
        if (s >= 4) poll16(myB, (unsigned)(s - 3), lane);  // ring back-pressure
      }
      __syncthreads();

      if (s >= 1) {
        const u16* p = h0ring + (size_t)((s - 1) & 3) * SLOT +
                       fragoff(Rw, 0, lane);
#pragma unroll
        for (int kk = 0; kk < 16; ++kk) hf[kk] = ld_h8(p + (size_t)kk * 512);
      }

      f32x4 a0 = {bias[0], bias[0], bias[0], bias[0]};
      f32x4 a1 = {bias[1], bias[1], bias[1], bias[1]};
      bf16x8 xf[2];
      if (usexf) {
#pragma unroll
        for (int kk = 0; kk < 2; ++kk)
          xf[kk] = __builtin_bit_cast(bf16x8, xpre[kk]);
        const size_t sp = (size_t)((s + 1) & 511);
#pragma unroll
        for (int kk = 0; kk < 2; ++kk)
          xpre[kk] = *(const ushort8*)(xfrag + (sp * 16 + Rw) * 1024 +
                                       (size_t)kk * 512 + lane * 8);
      } else {
#pragma unroll
        for (int kk = 0; kk < 2; ++kk) {
          ushort8 t;
#pragma unroll
          for (int j = 0; j < 8; ++j) t[j] = f2bf(xr[kk * 8 + j]);
          xf[kk] = __builtin_bit_cast(bf16x8, t);
        }
        const size_t sp = (size_t)((s + 1) & 511);
#pragma unroll
        for (int j = 0; j < 16; ++j)
          xr[j] = xbase[sp * II + (j >> 3) * 32 + (j & 7)];
      }
#pragma unroll
      for (int kk = 0; kk < 2; ++kk) {
        bf16x8 bA = ld_lds8(&wsm[cc * 600 + kk * 32 + lb]);
        bf16x8 bB = ld_lds8(&wsm[(16 + cc) * 600 + kk * 32 + lb]);
        a0 = mfma16(xf[kk], bA, a0);
        a1 = mfma16(xf[kk], bB, a1);
      }
      if (s >= 1) {
#pragma unroll
        for (int kk = 0; kk < 16; ++kk) {
          bf16x8 bA = ld_lds8(&wsm[cc * 600 + (kk + 2) * 32 + lb]);
          bf16x8 bB = ld_lds8(&wsm[(16 + cc) * 600 + (kk + 2) * 32 + lb]);
          a0 = mfma16(hf[kk], bA, a0);
          a1 = mfma16(hf[kk], bB, a1);
        }
      }
      // ---- cell -> store h0[s] (ring slot s&3) ----
      u16* h0wr = h0ring + (size_t)(s & 3) * SLOT;
#pragma unroll
      for (int r = 0; r < 4; ++r) {
        float f_p = __shfl_xor(a0[r], 8);
        float o_p = __shfl_xor(a1[r], 8);
        float ig = sigmf(a0[r]);
        float fg = sigmf(f_p);
        float gg = tanh_s(a1[r]);
        float og = sigmf(o_p);
        float cn = fg * c[r] + ig * gg;
        c[r] = cn;
        float hv = og * tanh_s(cn);
        unsigned myb = f2bf(hv);
        unsigned nb = (unsigned)__shfl_down((int)myb, 1);
        if (cc < 8 && (cc & 1) == 0) {
          unsigned* p = (unsigned*)(h0wr +
              fragoff(Rw, kkw, lpb + grp * 4 + r) + cc);
          __hip_atomic_store(p, myb | (nb << 16), __ATOMIC_RELAXED,
                             __HIP_MEMORY_SCOPE_AGENT);
        }
      }
      asm volatile("s_waitcnt vmcnt(0)" ::: "memory");  // stores acked
      if (lane == 0)
        __hip_atomic_store(&myA[ut * 4 + wid], (unsigned)(s + 1),
                           __ATOMIC_RELAXED, __HIP_MEMORY_SCOPE_AGENT);
    }
  } else {
    // ================= LAYER-1 WGs =================
#pragma unroll 1
    for (int s = 0; s < 512; ++s) {
      if (wid == 0) poll16(myA, (unsigned)(s + 1), lane);  // h0[s] visible
      __syncthreads();

      // phase 1: W_ih1 x h0[s] (no h1 dependency)
      {
        const u16* p = h0ring + (size_t)(s & 3) * SLOT + fragoff(Rw, 0, lane);
#pragma unroll
        for (int kk = 0; kk < 16; ++kk) hf[kk] = ld_h8(p + (size_t)kk * 512);
      }
      f32x4 a0 = {bias[0], bias[0], bias[0], bias[0]};
      f32x4 a1 = {bias[1], bias[1], bias[1], bias[1]};
#pragma unroll
      for (int kk = 0; kk < 16; ++kk) {
        bf16x8 bA = ld_lds8(&wsm[cc * 1048 + kk * 32 + lb]);
        bf16x8 bB = ld_lds8(&wsm[(16 + cc) * 1048 + kk * 32 + lb]);
        a0 = mfma16(hf[kk], bA, a0);
        a1 = mfma16(hf[kk], bB, a1);
      }
      // phase 2: W_hh1 x h1[s-1], pollB overlapped with phase 1 skew
      if (wid == 0 && s >= 1) poll16(myB, (unsigned)s, lane);
      __syncthreads();
      if (s >= 1) {
        const u16* p = h1ring + (size_t)((s - 1) & 3) * SLOT +
                       fragoff(Rw, 0, lane);
#pragma unroll
        for (int kk = 0; kk < 16; ++kk) hf[kk] = ld_h8(p + (size_t)kk * 512);
#pragma unroll
        for (int kk = 0; kk < 16; ++kk) {
          bf16x8 bA = ld_lds8(&wsm[cc * 1048 + (16 + kk) * 32 + lb]);
          bf16x8 bB = ld_lds8(&wsm[(16 + cc) * 1048 + (16 + kk) * 32 + lb]);
          a0 = mfma16(hf[kk], bA, a0);
          a1 = mfma16(hf[kk], bB, a1);
        }
      }
      // ---- cell -> store h1[s] (ring slot s&3) ----
      u16* h1wr = h1ring + (size_t)(s & 3) * SLOT;
#pragma unroll
      for (int r = 0; r < 4; ++r) {
        float f_p = __shfl_xor(a0[r], 8);
        float o_p = __shfl_xor(a1[r], 8);
        float ig = sigmf(a0[r]);
        float fg = sigmf(f_p);
        float gg = tanh_s(a1[r]);
        float og = sigmf(o_p);
        float cn = fg * c[r] + ig * gg;
        c[r] = cn;
        float hv = og * tanh_s(cn);
        unsigned myb = f2bf(hv);
        unsigned nb = (unsigned)__shfl_down((int)myb, 1);
        if (cc < 8 && (cc & 1) == 0) {
          unsigned* p = (unsigned*)(h1wr +
              fragoff(Rw, kkw, lpb + grp * 4 + r) + cc);
          __hip_atomic_store(p, myb | (nb << 16), __ATOMIC_RELAXED,
                             __HIP_MEMORY_SCOPE_AGENT);
        }
        if (cc < 8 && s == 511)
          h1fin[(size_t)(row0 + grp * 4 + r) * HH + u0 + cc] = hv;
      }
      asm volatile("s_waitcnt vmcnt(0)" ::: "memory");  // stores acked
      if (lane == 0)
        __hip_atomic_store(&myB[ut * 4 + wid], (unsigned)(s + 1),
                           __ATOMIC_RELAXED, __HIP_MEMORY_SCOPE_AGENT);
    }
  }
}

__global__ void fc_kernel(const float* __restrict__ h1fin,
                          const float* __restrict__ Wfc,
                          const float* __restrict__ bfc,
                          float* __restrict__ out) {
  const int wid = threadIdx.x >> 6, lane = threadIdx.x & 63;
  const int b = blockIdx.x * 4 + wid;
  float sum = 0.f;
#pragma unroll
  for (int j = 0; j < 8; ++j)
    sum += h1fin[(size_t)b * 512 + lane + 64 * j] * Wfc[lane + 64 * j];
#pragma unroll
  for (int m = 32; m; m >>= 1) sum += __shfl_xor(sum, m);
  if (lane == 0) out[b] = sum + bfc[0];
}

extern "C" void kernel_launch(void* const* d_in, const int* in_sizes, int n_in,
                              void* d_out, int out_size, void* d_ws, size_t ws_size,
                              hipStream_t stream) {
  const float* x    = (const float*)d_in[0];
  const float* Wih0 = (const float*)d_in[1];
  const float* Whh0 = (const float*)d_in[2];
  const float* bih0 = (const float*)d_in[3];
  const float* bhh0 = (const float*)d_in[4];
  const float* Wih1 = (const float*)d_in[5];
  const float* Whh1 = (const float*)d_in[6];
  const float* bih1 = (const float*)d_in[7];
  const float* bhh1 = (const float*)d_in[8];
  const float* Wfc  = (const float*)d_in[9];
  const float* bfc  = (const float*)d_in[10];

  char* ws = (char*)d_ws;
  u16* h0ring = (u16*)(ws);
  u16* h1ring = (u16*)(ws + OFF_H1RING);
  float* h1fin = (float*)(ws + OFF_H1FIN);
  unsigned* slotsA = (unsigned*)(ws + OFF_BAR);
  unsigned* slotsB = slotsA + 1024;
  u16* xfrag = (ws_size >= WS_NEED) ? (u16*)(ws + OFF_XFRAG) : nullptr;

  init_bar_k<<<1, 256, 0, stream>>>(slotsA);
  if (xfrag) xpose_k<<<4096, 256, 0, stream>>>(x, xfrag);

  void* args[] = {(void*)&x, (void*)&xfrag,
                  (void*)&Wih0, (void*)&Whh0, (void*)&bih0, (void*)&bhh0,
                  (void*)&Wih1, (void*)&Whh1, (void*)&bih1, (void*)&bhh1,
                  (void*)&h0ring, (void*)&h1ring, (void*)&h1fin,
                  (void*)&slotsA, (void*)&slotsB};
  hipError_t ce = hipLaunchCooperativeKernel((const void*)lstm_split,
                                             dim3(512), dim3(256), args, 0,
                                             stream);
  if (ce != hipSuccess) {
    // fallback: plain launch (512 WGs at 2/CU fit by resource arithmetic)
    lstm_split<<<512, 256, 0, stream>>>(x, xfrag, Wih0, Whh0, bih0, bhh0,
                                        Wih1, Whh1, bih1, bhh1,
                                        h0ring, h1ring, h1fin, slotsA, slotsB);
  }
  fc_kernel<<<64, 256, 0, stream>>>(h1fin, Wfc, bfc, (float*)d_out);
}

// Round 10
// 3772.353 us; speedup vs baseline: 1.4831x; 1.4831x over previous
//
#include <hip/hip_runtime.h>

typedef __bf16 bf16x8 __attribute__((ext_vector_type(8)));
typedef float f32x4 __attribute__((ext_vector_type(4)));
typedef unsigned short u16;
typedef u16 ushort8 __attribute__((ext_vector_type(8)));

#define BB 256
#define TT 512
#define II 64
#define HH 512
#define SLOT 131072   // u16 per h ring slot (256 KB)

// ws layout:
// [0x000000) h0ring : 4 * 256KB (fragment-order bf16)
// [0x100000) h1ring : 2 * 256KB
// [0x180000) h1fin  : 256*512 f32
// [0x200000) slotsA : 1024 u32 ; slotsB at +4KB
// [0x210000) xfrag  : 16 MB (optional)
#define OFF_H1RING 0x100000
#define OFF_H1FIN  0x180000
#define OFF_BAR    0x200000
#define OFF_XFRAG  0x210000
#define WS_NEED    (0x210000 + (size_t)(1 << 24))

__device__ __forceinline__ u16 f2bf(float f) {
  unsigned u = __builtin_bit_cast(unsigned, f);
  u = (u + 0x7FFFu + ((u >> 16) & 1u)) >> 16;   // RNE truncate to bf16
  return (u16)u;
}
__device__ __forceinline__ float sigmf(float v) {
  return 1.0f / (1.0f + __expf(-v));
}
__device__ __forceinline__ float tanh_s(float v) {
  float a = __builtin_fabsf(v);
  float e = __expf(-2.0f * a);
  float t = (1.0f - e) / (1.0f + e);
  return __builtin_copysignf(t, v);
}
__device__ __forceinline__ f32x4 mfma16(bf16x8 a, bf16x8 b, f32x4 c) {
  return __builtin_amdgcn_mfma_f32_16x16x32_bf16(a, b, c, 0, 0, 0);
}
// fragment-order offset (u16 units): chunk (R, kk, lane) of 8 bf16
__device__ __forceinline__ size_t fragoff(int R, int kk, int lane) {
  return ((size_t)(R * 16 + kk) * 64 + lane) * 8;
}
// agent-scope (cross-XCD coherent) 16B chunk load as 2x8B relaxed atomics
__device__ __forceinline__ bf16x8 ld_h8(const u16* p) {
  union { unsigned long long q[2]; ushort8 v; } u;
  u.q[0] = __hip_atomic_load((unsigned long long*)p, __ATOMIC_RELAXED,
                             __HIP_MEMORY_SCOPE_AGENT);
  u.q[1] = __hip_atomic_load((unsigned long long*)(p + 4), __ATOMIC_RELAXED,
                             __HIP_MEMORY_SCOPE_AGENT);
  return __builtin_bit_cast(bf16x8, u.v);
}
__device__ __forceinline__ bf16x8 ld_lds8(const u16* p) {
  return __builtin_bit_cast(bf16x8, *(const ushort8*)p);
}
// per-wave row poll: lane l checks row[l] >= tgt; 64x4B coalesced
__device__ __forceinline__ void pollrow(const unsigned* row, unsigned tgt,
                                        int lane) {
  const unsigned* p = row + lane;
  for (;;) {
    unsigned v = __hip_atomic_load(p, __ATOMIC_RELAXED,
                                   __HIP_MEMORY_SCOPE_AGENT);
    if (__all(v >= tgt)) break;
    __builtin_amdgcn_s_sleep(2);
  }
}

__global__ void init_bar_k(unsigned* bar) {
  for (int i = threadIdx.x; i < 2048; i += blockDim.x) bar[i] = 0u;
}

// x -> fragment-order bf16: xfrag[t][R][kk][lane][8], one thread per chunk.
__global__ void xpose_k(const float* __restrict__ x, u16* __restrict__ xfrag) {
  const size_t idx = (size_t)blockIdx.x * 256 + threadIdx.x;  // 2^20 chunks
  const int lane = idx & 63;
  const int kk = (idx >> 6) & 1;
  const int R = (idx >> 7) & 15;
  const int t = (int)(idx >> 11);
  const int row = R * 16 + (lane & 15);
  const int col = kk * 32 + (lane >> 4) * 8;
  const float* src = x + ((size_t)row * TT + t) * II + col;
  ushort8 v;
#pragma unroll
  for (int j = 0; j < 8; ++j) v[j] = f2bf(src[j]);
  *(ushort8*)(xfrag + idx * 8) = v;
}

// Persistent fused 2-layer LSTM, lag-1 shadow, per-wave sync. grid=256,
// block=256 (4 waves). WG(bid): bt=bid>>6, ut=bid&63 (8 units). Wave wid owns
// rows Rw=bt*4+wid (16 rows).
// Iter s: L0 computes t=s using hcur=h0[s-1]; SHADOW computes L1 t=s-1 using
// the SAME hcur (register reuse, no reload) + h1[s-2] (pollB-guarded, loads
// issued before the 32 register-fed ih-MFMAs so the RTT hides under them).
// Sync is fully per-wave: wave wid only consumes chunks written by peer waves
// of the same wid (fragoff R=Rw mapping), so slots[bt][wid][ut] rows suffice;
// each wave arrives (lane0 store) + polls its own coalesced 64-entry row.
// NO __syncthreads in the loop. Rings: h0 4-deep, h1 2-deep.
//   safety: pollA(s) => peers finished L0[s-1] => past ring reads of h0[<=s-2];
//   pollB(s) => peers finished iter s-1 shadow => h1[s-2] complete and
//   h1[s-3] readers done before my h1[s-1] overwrite. DAG increases in s.
__global__ __launch_bounds__(256, 1) void lstm_persist(
    const float* __restrict__ x, const u16* __restrict__ xfrag,
    const float* __restrict__ Wih0, const float* __restrict__ Whh0,
    const float* __restrict__ bih0, const float* __restrict__ bhh0,
    const float* __restrict__ Wih1, const float* __restrict__ Whh1,
    const float* __restrict__ bih1, const float* __restrict__ bhh1,
    u16* __restrict__ h0ring, u16* __restrict__ h1ring,
    float* __restrict__ h1fin, unsigned* __restrict__ slotsA,
    unsigned* __restrict__ slotsB) {
  __shared__ u16 w0s[32 * 600];
  __shared__ u16 w1s[32 * 1048];

  const int tid = threadIdx.x;
  const int lane = tid & 63;
  const int wid = tid >> 6;
  const int bid = blockIdx.x;
  const int ut = bid & 63, bt = bid >> 6;
  const int u0 = ut * 8;
  const int cc = lane & 15, grp = lane >> 4;

  unsigned* rowA = slotsA + (size_t)bt * 256 + wid * 64;  // my wave's row
  unsigned* rowB = slotsB + (size_t)bt * 256 + wid * 64;

  // ---- stage W0 slice (32 gate-rows x 576) into LDS as bf16 ----
  {
    const int srow = tid >> 3, sub = tid & 7;
    const int g = (srow >> 3) * 512 + u0 + (srow & 7);
    const float* wih = Wih0 + (size_t)g * 64;
    const float* whh = Whh0 + (size_t)g * 512;
    const int e0 = sub * 72;
    for (int e = e0; e < e0 + 72; ++e) {
      float v = (e < 64) ? wih[e] : whh[e - 64];
      w0s[srow * 600 + e] = f2bf(v);
    }
  }
  // ---- stage W1 slice (32 gate-rows x 1024) into LDS as bf16 ----
  {
    const int srow = tid >> 3, sub = tid & 7;
    const int g = (srow >> 3) * 512 + u0 + (srow & 7);
    const float* wih = Wih1 + (size_t)g * 512;
    const float* whh = Whh1 + (size_t)g * 512;
    const int e0 = sub * 128;
    for (int e = e0; e < e0 + 128; ++e) {
      float v = (e < 512) ? wih[e] : whh[e - 512];
      w1s[srow * 1048 + e] = f2bf(v);
    }
  }

  float bias0[2], bias1[2];
#pragma unroll
  for (int nf = 0; nf < 2; ++nf) {
    const int srow = nf * 16 + cc;
    const int g = (srow >> 3) * 512 + u0 + (srow & 7);
    bias0[nf] = bih0[g] + bhh0[g];
    bias1[nf] = bih1[g] + bhh1[g];
  }

  const int row0 = bt * 64 + wid * 16;
  const int Rw = bt * 4 + wid;
  const int arow = row0 + cc;
  const float* xbase = x + (size_t)arow * (TT * II) + grp * 8;
  const bool usexf = (xfrag != nullptr);
  float c0[4] = {0.f, 0.f, 0.f, 0.f};
  float c1[4] = {0.f, 0.f, 0.f, 0.f};

  ushort8 xpre[2];
  float xr[16];
  if (usexf) {
#pragma unroll
    for (int kk = 0; kk < 2; ++kk)
      xpre[kk] = *(const ushort8*)(xfrag + (size_t)Rw * 1024 +
                                   (size_t)kk * 512 + lane * 8);
  } else {
#pragma unroll
    for (int j = 0; j < 16; ++j) xr[j] = xbase[(j >> 3) * 32 + (j & 7)];
  }

  const int kkw = ut >> 2, lpb = (ut & 3) * 16;   // writer chunk params
  const int lb = grp * 8;

  __syncthreads();   // weights staged (only sync in the kernel)

  bf16x8 hcur[16];   // h0[s-1]: loaded once, feeds L0 AND the lag-1 shadow

#pragma unroll 1
  for (int s = 0; s <= 512; ++s) {
    const bool doL0 = (s < 512);

    // ---- per-wave pollA(s): peers' h0[s-1] visible; then load it ----
    if (s >= 1) {
      pollrow(rowA, (unsigned)s, lane);
      const u16* p = h0ring + (size_t)((s - 1) & 3) * SLOT +
                     fragoff(Rw, 0, lane);
#pragma unroll
      for (int kk = 0; kk < 16; ++kk) hcur[kk] = ld_h8(p + (size_t)kk * 512);
    }

    // ======== critical path: layer0 t = s ========
    if (doL0) {
      f32x4 a00 = {bias0[0], bias0[0], bias0[0], bias0[0]};
      f32x4 a01 = {bias0[1], bias0[1], bias0[1], bias0[1]};
      bf16x8 xf[2];
      if (usexf) {
#pragma unroll
        for (int kk = 0; kk < 2; ++kk)
          xf[kk] = __builtin_bit_cast(bf16x8, xpre[kk]);
        const size_t sp = (size_t)((s + 1) & 511);
#pragma unroll
        for (int kk = 0; kk < 2; ++kk)
          xpre[kk] = *(const ushort8*)(xfrag + (sp * 16 + Rw) * 1024 +
                                       (size_t)kk * 512 + lane * 8);
      } else {
#pragma unroll
        for (int kk = 0; kk < 2; ++kk) {
          ushort8 t;
#pragma unroll
          for (int j = 0; j < 8; ++j) t[j] = f2bf(xr[kk * 8 + j]);
          xf[kk] = __builtin_bit_cast(bf16x8, t);
        }
        const size_t sp = (size_t)((s + 1) & 511);
#pragma unroll
        for (int j = 0; j < 16; ++j)
          xr[j] = xbase[sp * II + (j >> 3) * 32 + (j & 7)];
      }
#pragma unroll
      for (int kk = 0; kk < 2; ++kk) {
        bf16x8 bA = ld_lds8(&w0s[cc * 600 + kk * 32 + lb]);
        bf16x8 bB = ld_lds8(&w0s[(16 + cc) * 600 + kk * 32 + lb]);
        a00 = mfma16(xf[kk], bA, a00);
        a01 = mfma16(xf[kk], bB, a01);
      }
      if (s >= 1) {
#pragma unroll
        for (int kk = 0; kk < 16; ++kk) {
          bf16x8 bA = ld_lds8(&w0s[cc * 600 + (kk + 2) * 32 + lb]);
          bf16x8 bB = ld_lds8(&w0s[(16 + cc) * 600 + (kk + 2) * 32 + lb]);
          a00 = mfma16(hcur[kk], bA, a00);
          a01 = mfma16(hcur[kk], bB, a01);
        }
      }
      // ---- layer0 cell -> store h0[s] (ring slot s&3) ----
      u16* h0wr = h0ring + (size_t)(s & 3) * SLOT;
#pragma unroll
      for (int r = 0; r < 4; ++r) {
        float f_p = __shfl_xor(a00[r], 8);
        float o_p = __shfl_xor(a01[r], 8);
        float ig = sigmf(a00[r]);
        float fg = sigmf(f_p);
        float gg = tanh_s(a01[r]);
        float og = sigmf(o_p);
        float cn = fg * c0[r] + ig * gg;
        c0[r] = cn;
        float hv = og * tanh_s(cn);
        unsigned myb = f2bf(hv);
        unsigned nb = (unsigned)__shfl_down((int)myb, 1);
        if (cc < 8 && (cc & 1) == 0) {
          unsigned* p = (unsigned*)(h0wr +
              fragoff(Rw, kkw, lpb + grp * 4 + r) + cc);
          __hip_atomic_store(p, myb | (nb << 16), __ATOMIC_RELAXED,
                             __HIP_MEMORY_SCOPE_AGENT);
        }
      }
      asm volatile("s_waitcnt vmcnt(0)" ::: "memory");  // h0 stores acked
      if (lane == 0)
        __hip_atomic_store(&rowA[ut], (unsigned)(s + 1), __ATOMIC_RELAXED,
                           __HIP_MEMORY_SCOPE_AGENT);
    }

    // ======== shadow: layer1 t = s-1, h0-input = hcur (registers) ========
    if (s >= 1) {
      // pollB(s) then ISSUE h1[s-2] loads; RTT hides under ih-MFMAs below
      bf16x8 h1f[16];
      if (s >= 2) {
        pollrow(rowB, (unsigned)s, lane);
        const u16* p = h1ring + (size_t)((s - 2) & 1) * SLOT +
                       fragoff(Rw, 0, lane);
#pragma unroll
        for (int kk = 0; kk < 16; ++kk) h1f[kk] = ld_h8(p + (size_t)kk * 512);
      }
      f32x4 a10 = {bias1[0], bias1[0], bias1[0], bias1[0]};
      f32x4 a11 = {bias1[1], bias1[1], bias1[1], bias1[1]};
      // W_ih1 x h0[s-1] (hcur, registers; B from LDS)
#pragma unroll
      for (int kk = 0; kk < 16; ++kk) {
        bf16x8 bA = ld_lds8(&w1s[cc * 1048 + kk * 32 + lb]);
        bf16x8 bB = ld_lds8(&w1s[(16 + cc) * 1048 + kk * 32 + lb]);
        a10 = mfma16(hcur[kk], bA, a10);
        a11 = mfma16(hcur[kk], bB, a11);
      }
      // W_hh1 x h1[s-2]
      if (s >= 2) {
#pragma unroll
        for (int kk = 0; kk < 16; ++kk) {
          bf16x8 bA = ld_lds8(&w1s[cc * 1048 + (16 + kk) * 32 + lb]);
          bf16x8 bB = ld_lds8(&w1s[(16 + cc) * 1048 + (16 + kk) * 32 + lb]);
          a10 = mfma16(h1f[kk], bA, a10);
          a11 = mfma16(h1f[kk], bB, a11);
        }
      }
      // ---- layer1 cell -> store h1[s-1] (slot (s-1)&1) ----
      u16* h1wr = h1ring + (size_t)((s - 1) & 1) * SLOT;
#pragma unroll
      for (int r = 0; r < 4; ++r) {
        float f_p = __shfl_xor(a10[r], 8);
        float o_p = __shfl_xor(a11[r], 8);
        float ig = sigmf(a10[r]);
        float fg = sigmf(f_p);
        float gg = tanh_s(a11[r]);
        float og = sigmf(o_p);
        float cn = fg * c1[r] + ig * gg;
        c1[r] = cn;
        float hv = og * tanh_s(cn);
        unsigned myb = f2bf(hv);
        unsigned nb = (unsigned)__shfl_down((int)myb, 1);
        if (cc < 8 && (cc & 1) == 0) {
          unsigned* p = (unsigned*)(h1wr +
              fragoff(Rw, kkw, lpb + grp * 4 + r) + cc);
          __hip_atomic_store(p, myb | (nb << 16), __ATOMIC_RELAXED,
                             __HIP_MEMORY_SCOPE_AGENT);
        }
        if (cc < 8 && s == 512)
          h1fin[(size_t)(row0 + grp * 4 + r) * HH + u0 + cc] = hv;
      }
      asm volatile("s_waitcnt vmcnt(0)" ::: "memory");  // h1 stores acked
      if (lane == 0)
        __hip_atomic_store(&rowB[ut], (unsigned)(s + 1), __ATOMIC_RELAXED,
                           __HIP_MEMORY_SCOPE_AGENT);
    }
  }
}

__global__ void fc_kernel(const float* __restrict__ h1fin,
                          const float* __restrict__ Wfc,
                          const float* __restrict__ bfc,
                          float* __restrict__ out) {
  const int wid = threadIdx.x >> 6, lane = threadIdx.x & 63;
  const int b = blockIdx.x * 4 + wid;
  float sum = 0.f;
#pragma unroll
  for (int j = 0; j < 8; ++j)
    sum += h1fin[(size_t)b * 512 + lane + 64 * j] * Wfc[lane + 64 * j];
#pragma unroll
  for (int m = 32; m; m >>= 1) sum += __shfl_xor(sum, m);
  if (lane == 0) out[b] = sum + bfc[0];
}

extern "C" void kernel_launch(void* const* d_in, const int* in_sizes, int n_in,
                              void* d_out, int out_size, void* d_ws, size_t ws_size,
                              hipStream_t stream) {
  const float* x    = (const float*)d_in[0];
  const float* Wih0 = (const float*)d_in[1];
  const float* Whh0 = (const float*)d_in[2];
  const float* bih0 = (const float*)d_in[3];
  const float* bhh0 = (const float*)d_in[4];
  const float* Wih1 = (const float*)d_in[5];
  const float* Whh1 = (const float*)d_in[6];
  const float* bih1 = (const float*)d_in[7];
  const float* bhh1 = (const float*)d_in[8];
  const float* Wfc  = (const float*)d_in[9];
  const float* bfc  = (const float*)d_in[10];

  char* ws = (char*)d_ws;
  u16* h0ring = (u16*)(ws);
  u16* h1ring = (u16*)(ws + OFF_H1RING);
  float* h1fin = (float*)(ws + OFF_H1FIN);
  unsigned* slotsA = (unsigned*)(ws + OFF_BAR);
  unsigned* slotsB = slotsA + 1024;
  u16* xfrag = (ws_size >= WS_NEED) ? (u16*)(ws + OFF_XFRAG) : nullptr;

  init_bar_k<<<1, 256, 0, stream>>>(slotsA);
  if (xfrag) xpose_k<<<4096, 256, 0, stream>>>(x, xfrag);
  lstm_persist<<<256, 256, 0, stream>>>(x, xfrag, Wih0, Whh0, bih0, bhh0,
                                        Wih1, Whh1, bih1, bhh1,
                                        h0ring, h1ring, h1fin, slotsA, slotsB);
  fc_kernel<<<64, 256, 0, stream>>>(h1fin, Wfc, bfc, (float*)d_out);
}